// Round 5
// baseline (300.646 us; speedup 1.0000x reference)
//
#include <hip/hip_runtime.h>

#define SEQ   256
#define FEAT  768
#define FILT  6
#define WELEMS (2304 * FILT)       // 13824 floats per s

typedef _Float16 f16x8 __attribute__((ext_vector_type(8)));  // MFMA A/B frag
typedef __attribute__((ext_vector_type(4))) float f32x4;     // MFMA C/D

// R10: K-split-2 for TLP. R9 proved latency-bound: cutting per-step cost 35%
// (3->2 MFMA, 2->1 ds_read) moved nothing (~97us); traffic is at x-once
// floor (~210MB -> 33-50us service). Occupancy was GRID-limited: 512x8
// waves = 4 waves/SIMD. Now: 1024-thr blocks, wave = (mtile 0..7, khalf);
// each K-half wave does 12 of 24 K-steps per band on the same 16-batch
// tile -> 32 waves/CU (8/SIMD), 2x outstanding misses. K-halves share the
// C/D layout, so the merge is one 8KB-LDS add at the end (1 extra barrier,
// not per-group). Prefetch depth 6->3 to fit the 64-VGPR cap imposed by
// __launch_bounds__(1024,8) (est ~56: queue 24 + frags 12 + acc 8 + addr).
// Kept: per-s skinny GEMM via mfma_f32_16x16x32_f16, 2-term f16 split
// (x = xh + xl exact; W RTN once); mod-3 band phasing (row r read by all
// consumers in phase r%3); XCD-contiguous s swizzle; C/D col=lane&15,
// row=4*(lane>>4)+reg (HW-verified R7-R9).
__global__ __launch_bounds__(1024, 8)
void pos_linear_kernel(const float* __restrict__ x,
                       const float* __restrict__ W,
                       const float* __restrict__ bias,
                       float* __restrict__ out) {
    // f16 frag for k-step t, k-group h, col c: shorts[((4t+h)*6 + c)*8 + e]
    __shared__ __align__(16) unsigned short wf[13824];
    __shared__ float red[4][8 * 64];   // [g][mt*64+lane]: stride-1, no conflict

    const int blk   = blockIdx.x;
    const int halfb = blk >> 8;                     // batch half 0/1
    const int sb    = blk & 255;
    const int s     = ((sb & 7) << 5) | (sb >> 3);  // XCD-contiguous s ranges
    const int tid   = threadIdx.x;

    // ---- Stage W[s] -> f16 fragments in LDS (one-time, RTN convert) ----
    {
        const float* Ws = W + (size_t)s * WELEMS;
        for (int k = tid; k < 2304; k += 1024) {
            const int slot8 = (k >> 3) * 6;         // (4t+h)*6
            const int e     = k & 7;
            #pragma unroll
            for (int o = 0; o < FILT; ++o) {
                _Float16 hv = (_Float16)Ws[k * FILT + o];
                wf[(slot8 + o) * 8 + e] = *(const unsigned short*)&hv;
            }
        }
    }
    __syncthreads();

    const int lane = tid & 63;
    const int wave = tid >> 6;        // 0..15
    const int kv   = wave & 1;        // K-half 0/1
    const int mt   = wave >> 1;       // M-tile 0..7
    const int row  = lane & 15;       // batch within M-tile (A side)
    const int h    = lane >> 4;       // k-group 0..3
    const int col  = lane & 15;       // output col (valid < 6, B side)
    const bool cv  = col < FILT;
    const int b0   = (halfb << 7) + (mt << 4);      // tile batch base

    // invalid lanes clamp to col 5: in-bounds garbage -> D cols >=6 only
    const int bidx = (6 * h + (cv ? col : 5)) * 8;  // B-frag short base

    f32x4 acc_h = {0, 0, 0, 0};
    f32x4 acc_l = {0, 0, 0, 0};

    // per-lane x base: batch (b0+row), feature offset 8h; band adds r*FEAT
    const float* xb = x + (size_t)(b0 + row) * (SEQ * FEAT) + 8 * h;

    // one K-step: split 8 floats -> f16 hi/lo frags, read B frag, 2 MFMA
    auto step = [&](f32x4 u, f32x4 v, int tg) {
        f16x8 ah, al;
        #pragma unroll
        for (int e = 0; e < 8; ++e) {
            float f = (e < 4) ? u[e] : v[e - 4];
            _Float16 hh = (_Float16)f;              // RTN
            ah[e] = hh;
            al[e] = (_Float16)(f - (float)hh);      // exact residual -> f16
        }
        f16x8 bw = *(const f16x8*)&wf[bidx + 192 * tg];
        acc_h = __builtin_amdgcn_mfma_f32_16x16x32_f16(ah, bw, acc_h, 0, 0, 0);
        acc_l = __builtin_amdgcn_mfma_f32_16x16x32_f16(al, bw, acc_l, 0, 0, 0);
    };

    // 3 phases; phase p handles band w with r = s-1+w, r % 3 == p
    // (w = (p - s + 256) % 3). Band skip at edges == zero padding.
    // Within a band this wave covers global K-steps [12kv, 12kv+12).
    #pragma unroll
    for (int p = 0; p < 3; ++p) {
        const int w = (p - s + 256) % 3;
        const int r = s - 1 + w;
        if (r >= 0 && r < SEQ) {                    // block-uniform
            const f32x4* ap = (const f32x4*)(xb + (size_t)r * FEAT) + 96 * kv;
            const int tb = 24 * w + 12 * kv;

            // depth-3 circular prefetch (6 dwordx4 in flight; TLP does rest)
            f32x4 qa[3], qb[3];
            #pragma unroll
            for (int t = 0; t < 3; ++t) { qa[t] = ap[8 * t]; qb[t] = ap[8 * t + 1]; }
            #pragma unroll
            for (int t = 0; t < 12; ++t) {          // full unroll: t%3 static
                f32x4 u = qa[t % 3], v = qb[t % 3];
                if (t + 3 < 12) {
                    qa[t % 3] = ap[8 * (t + 3)];
                    qb[t % 3] = ap[8 * (t + 3) + 1];
                }
                step(u, v, tb + t);
            }
        }
        __syncthreads();   // phase alignment (3 barriers)
    }

    // ---- K-half merge: kv=1 parks partials in LDS, kv=0 finalizes ----
    // C/D: col = lane&15, row = 4*(lane>>4) + reg  [HW-verified mapping]
    if (kv) {
        #pragma unroll
        for (int g = 0; g < 4; ++g)
            red[g][mt * 64 + lane] = acc_h[g] + acc_l[g];
    }
    __syncthreads();
    if (!kv && cv) {
        const float bv = bias[s * FILT + col];
        #pragma unroll
        for (int g = 0; g < 4; ++g) {
            const int b = b0 + 4 * h + g;
            float vsum = acc_h[g] + acc_l[g] + red[g][mt * 64 + lane] + bv;
            vsum = vsum > 0.f ? vsum : 0.f;
            out[((size_t)b * SEQ + s) * FILT + col] = vsum;
        }
    }
}

extern "C" void kernel_launch(void* const* d_in, const int* in_sizes, int n_in,
                              void* d_out, int out_size, void* d_ws, size_t ws_size,
                              hipStream_t stream) {
    const float* x   = (const float*)d_in[0];  // (256, 256, 768) fp32
    const float* W   = (const float*)d_in[1];  // (256, 2304, 6) fp32
    const float* b   = (const float*)d_in[2];  // (256, 6) fp32
    float*       out = (float*)d_out;          // (256, 256, 6) fp32
    (void)in_sizes; (void)n_in; (void)out_size; (void)d_ws; (void)ws_size;
    pos_linear_kernel<<<SEQ * 2, 1024, 0, stream>>>(x, W, b, out);
}